// Round 14
// baseline (161.886 us; speedup 1.0000x reference)
//
#include <hip/hip_runtime.h>
#include <stdint.h>

#define CB 32
#define CT 512
#define CK 256
#define TMID 256
#define SHIFT 5.0f
#define EXP_NEG_SHIFT 0.006737946999085467f   // e^-5

typedef _Float16 f16x8 __attribute__((ext_vector_type(8)));
typedef float f32x4 __attribute__((ext_vector_type(4)));

__device__ inline uint32_t pk2(float a, float b) {
    return __builtin_bit_cast(uint32_t,
        __builtin_amdgcn_cvt_pkrtz(__expf(a), __expf(b)));
}

// Barrier draining LDS only; global prefetches stay in flight.
__device__ inline void lds_barrier() {
    asm volatile("s_waitcnt lgkmcnt(0)\n\ts_barrier" ::: "memory");
}

template <int CTRL>
__device__ inline float dpp_maxf(float x) {
    int yi = __builtin_amdgcn_update_dpp(
        __builtin_bit_cast(int, x), __builtin_bit_cast(int, x),
        CTRL, 0xF, 0xF, false);
    return fmaxf(x, __builtin_bit_cast(float, yi));
}

// Full wave64 max via DPP inclusive scan + readlane 63.
__device__ inline float wave_max(float x) {
    x = dpp_maxf<0x111>(x);
    x = dpp_maxf<0x112>(x);
    x = dpp_maxf<0x114>(x);
    x = dpp_maxf<0x118>(x);
    x = dpp_maxf<0x142>(x);
    x = dpp_maxf<0x143>(x);
    return __builtin_bit_cast(float,
        __builtin_amdgcn_readlane(__builtin_bit_cast(int, x), 63));
}

// FWD B-frag (kt,n): B[k][col] = exp(trans[k][col]); strided rows of trans.
#define MKB_F(kt, n) f16x8 B_##kt##_##n; {                                   \
    const float* tp = trans + (size_t)((kt) * 32 + ko8) * CK + (colg + (n) * 16); \
    uint4 u_;                                                                \
    u_.x = pk2(tp[0],      tp[CK]);                                          \
    u_.y = pk2(tp[2 * CK], tp[3 * CK]);                                      \
    u_.z = pk2(tp[4 * CK], tp[5 * CK]);                                      \
    u_.w = pk2(tp[6 * CK], tp[7 * CK]);                                      \
    B_##kt##_##n = __builtin_bit_cast(f16x8, u_); }

// BWD B-frag (kt,n): B[k][col] = exp(trans[col][k]) (contiguous k).
#define MKB_B(kt, n) f16x8 B_##kt##_##n; {                                   \
    const float* tp = trans + (size_t)(colg + (n) * 16) * CK + ((kt) * 32 + ko8); \
    uint4 u_;                                                                \
    u_.x = pk2(tp[0], tp[1]);                                                \
    u_.y = pk2(tp[2], tp[3]);                                                \
    u_.z = pk2(tp[4], tp[5]);                                                \
    u_.w = pk2(tp[6], tp[7]);                                                \
    B_##kt##_##n = __builtin_bit_cast(f16x8, u_); }

#define LOADB(MK) MK(0,0) MK(0,1) MK(1,0) MK(1,1) MK(2,0) MK(2,1) MK(3,0) MK(3,1) \
                  MK(4,0) MK(4,1) MK(5,0) MK(5,1) MK(6,0) MK(6,1) MK(7,0) MK(7,1)

// 4 independent chains, depth 4 each (acA0/acA1 for n=0, acB0/acB1 for n=1).
#define MMp(kt, ka, kb)                                                      \
    acA0 = __builtin_amdgcn_mfma_f32_16x16x32_f16(a##kt##_, B_##kt##_0, acA0, 0, 0, 0); \
    acB0 = __builtin_amdgcn_mfma_f32_16x16x32_f16(a##kt##_, B_##kt##_1, acB0, 0, 0, 0); \
    acA1 = __builtin_amdgcn_mfma_f32_16x16x32_f16(a##ka##_, B_##ka##_0, acA1, 0, 0, 0); \
    acB1 = __builtin_amdgcn_mfma_f32_16x16x32_f16(a##kb##_, B_##kb##_1, acB1, 0, 0, 0);

#define MFMA_STEP(pb)                                                        \
    f16x8 a0_ = *reinterpret_cast<const f16x8*>((pb) + 0   + ko8);           \
    f16x8 a1_ = *reinterpret_cast<const f16x8*>((pb) + 32  + ko8);           \
    f16x8 a2_ = *reinterpret_cast<const f16x8*>((pb) + 64  + ko8);           \
    f16x8 a3_ = *reinterpret_cast<const f16x8*>((pb) + 96  + ko8);           \
    f16x8 a4_ = *reinterpret_cast<const f16x8*>((pb) + 128 + ko8);           \
    f16x8 a5_ = *reinterpret_cast<const f16x8*>((pb) + 160 + ko8);           \
    f16x8 a6_ = *reinterpret_cast<const f16x8*>((pb) + 192 + ko8);           \
    f16x8 a7_ = *reinterpret_cast<const f16x8*>((pb) + 224 + ko8);           \
    f32x4 acA0 = {0.f, 0.f, 0.f, 0.f}, acA1 = {0.f, 0.f, 0.f, 0.f};         \
    f32x4 acB0 = {0.f, 0.f, 0.f, 0.f}, acB1 = {0.f, 0.f, 0.f, 0.f};         \
    MMp(0, 4, 4) MMp(1, 5, 5) MMp(2, 6, 6) MMp(3, 7, 7)

// 512 threads = 8 waves. Wave w owns states w*32..+31; lane l: sj = w*32+nsel*16+(l&15).
// Linear-domain: u = exp(alpha - Mref). ONE barrier/step; exp/log off critical path.
// ws: [0..31] logZ | [32..63] numerator | [64..) alpha_mid | [64+8192..) beta_mid
__global__ __launch_bounds__(512, 1) void crf_main_kernel(
    const float* __restrict__ emissions,    // [B,T,K]
    const int* __restrict__ tags,           // [B,T]
    const int* __restrict__ mask,           // [B,T] (bool -> int32)
    const float* __restrict__ trans,        // [K,K]
    float* __restrict__ ws)
{
    const int tid = threadIdx.x;
    const int w = tid >> 6;
    const int l = tid & 63;
    const int ko8 = ((l >> 4) & 3) * 8;
    const int colg = w * 32 + (l & 15);
    const int nsel = (l >> 4) & 1;
    const int sj = w * 32 + nsel * 16 + (l & 15);

    __shared__ __align__(16) _Float16 pbuf[2][CK];
    __shared__ __align__(16) float wmaxl[2][8];
    __shared__ float mask_lds[CT];
    __shared__ float red[8];

    if (blockIdx.x < CB) {
        // ======================= FORWARD (alpha) =======================
        const int b = blockIdx.x;
        const float* emB = emissions + (size_t)b * CT * CK;
        const int* tagB = tags + b * CT;
        const int* maskB = mask + b * CT;

        {   // numerator (one t per thread; CT == 512) + mask staging
            const int t = tid;
            float mf = maskB[t] ? 1.f : 0.f;
            float num = emB[(size_t)t * CK + tagB[t]] * mf;
            if (t >= 1) num += trans[(size_t)tagB[t - 1] * CK + tagB[t]] * mf;
            #pragma unroll
            for (int off = 32; off > 0; off >>= 1) num += __shfl_down(num, off, 64);
            if (l == 0) red[w] = num;
            mask_lds[tid] = mf;
            __syncthreads();
            if (tid == 0) {
                float s = 0.f;
                #pragma unroll
                for (int q = 0; q < 8; ++q) s += red[q];
                ws[CB + b] = s;
            }
        }

        LOADB(MKB_F)

        const float a0v = emB[sj];
        float emit_next = emB[CK + sj];

        // prologue: exact global max -> Mref, u = exp(alpha - Mref)
        {
            const float mw = wave_max(a0v);
            if (l == 0) wmaxl[0][w] = mw;
        }
        __syncthreads();
        float Mref;
        {
            const float4 wa = *reinterpret_cast<const float4*>(&wmaxl[0][0]);
            const float4 wb = *reinterpret_cast<const float4*>(&wmaxl[0][4]);
            Mref = fmaxf(fmaxf(fmaxf(wa.x, wa.y), fmaxf(wa.z, wa.w)),
                         fmaxf(fmaxf(wb.x, wb.y), fmaxf(wb.z, wb.w))) + SHIFT;
        }
        __syncthreads();   // protect wmaxl[0] reuse at t=2
        float u = __expf(a0v - Mref);
        float wmu = wave_max(u);

        for (int t = 1; t < TMID; ++t) {
            const float emit_t = emit_next;
            const int nxt = (t + 1 < TMID) ? (t + 1) : (TMID - 1);
            emit_next = emB[(size_t)nxt * CK + sj];
            const float ee_t = __expf(emit_t);
            const int bsel = t & 1;

            if (l == 0) wmaxl[bsel][w] = wmu;
            if (l < 32) pbuf[bsel][w * 32 + l] = (_Float16)u;
            lds_barrier();

            // concurrent with MFMA: G -> fD, Mref advance (all off MFMA pipe)
            const float4 wa = *reinterpret_cast<const float4*>(&wmaxl[bsel][0]);
            const float4 wb = *reinterpret_cast<const float4*>(&wmaxl[bsel][4]);
            const float G = fmaxf(fmaxf(fmaxf(wa.x, wa.y), fmaxf(wa.z, wa.w)),
                                  fmaxf(fmaxf(wb.x, wb.y), fmaxf(wb.z, wb.w)));
            const float fD = __builtin_amdgcn_rcpf(G) * EXP_NEG_SHIFT;
            Mref += __logf(G) + SHIFT;

            MFMA_STEP(pbuf[bsel])
            const float s = nsel ? (acB0[0] + acB1[0]) : (acA0[0] + acA1[0]);
            u = fD * ((mask_lds[t] != 0.f) ? s * ee_t : u);
            wmu = wave_max(u);
        }
        if (l < 32) ws[2 * CB + b * CK + w * 32 + l] = Mref + __logf(u);   // alpha_mid
    } else {
        // ======================= BACKWARD (beta) =======================
        const int b = blockIdx.x - CB;
        const float* emB = emissions + (size_t)b * CT * CK;
        const int* maskB = mask + b * CT;

        mask_lds[tid] = maskB[tid] ? 1.f : 0.f;

        LOADB(MKB_B)

        float emit_next = emB[(size_t)(CT - 1) * CK + sj];
        __syncthreads();   // mask_lds ready

        // prologue: v = 0 + emit(CT-1); exact max -> Mref; u_beta = exp(0 - Mref)
        {
            const float mw = wave_max(emit_next);
            if (l == 0) wmaxl[0][w] = mw;
        }
        __syncthreads();
        float Mref;
        {
            const float4 wa = *reinterpret_cast<const float4*>(&wmaxl[0][0]);
            const float4 wb = *reinterpret_cast<const float4*>(&wmaxl[0][4]);
            Mref = fmaxf(fmaxf(fmaxf(wa.x, wa.y), fmaxf(wa.z, wa.w)),
                         fmaxf(fmaxf(wb.x, wb.y), fmaxf(wb.z, wb.w))) + SHIFT;
        }
        __syncthreads();   // protect wmaxl[0] reuse
        float ub = __expf(0.f - Mref);

        for (int tn = CT - 1; tn >= TMID; --tn) {
            const float emit_t = emit_next;
            const int nxt = (tn - 1 > TMID) ? (tn - 1) : TMID;
            emit_next = emB[(size_t)nxt * CK + sj];
            const int bsel = tn & 1;

            const float ee_t = __expf(emit_t);
            const float q = ub * ee_t;           // exp(beta + emit - Mref)
            const float wmq = wave_max(q);
            if (l == 0) wmaxl[bsel][w] = wmq;
            if (l < 32) pbuf[bsel][w * 32 + l] = (_Float16)q;
            lds_barrier();

            const float4 wa = *reinterpret_cast<const float4*>(&wmaxl[bsel][0]);
            const float4 wb = *reinterpret_cast<const float4*>(&wmaxl[bsel][4]);
            const float G = fmaxf(fmaxf(fmaxf(wa.x, wa.y), fmaxf(wa.z, wa.w)),
                                  fmaxf(fmaxf(wb.x, wb.y), fmaxf(wb.z, wb.w)));
            const float fD = __builtin_amdgcn_rcpf(G) * EXP_NEG_SHIFT;
            Mref += __logf(G) + SHIFT;

            MFMA_STEP(pbuf[bsel])
            const float s = nsel ? (acB0[0] + acB1[0]) : (acA0[0] + acA1[0]);
            ub = fD * ((mask_lds[tn] != 0.f) ? s : ub);
        }
        if (l < 32) ws[2 * CB + CB * CK + b * CK + w * 32 + l] = Mref + __logf(ub);
    }
}

// logZ_b = LSE_j(alpha_mid[b][j] + beta_mid[b][j])
__global__ void crf_combine_kernel(float* __restrict__ ws) {
    const int b = blockIdx.x;
    const int tid = threadIdx.x;                 // 256 threads, 4 waves
    const int wid = tid >> 6, lane = tid & 63;
    __shared__ float red[8];
    const float v = ws[2 * CB + b * CK + tid] + ws[2 * CB + CB * CK + b * CK + tid];
    float mx = v;
    #pragma unroll
    for (int off = 32; off > 0; off >>= 1) mx = fmaxf(mx, __shfl_down(mx, off, 64));
    mx = __shfl(mx, 0, 64);
    if (lane == 0) red[wid] = mx;
    __syncthreads();
    const float gmx = fmaxf(fmaxf(red[0], red[1]), fmaxf(red[2], red[3]));
    float ex = __expf(v - gmx);
    #pragma unroll
    for (int off = 32; off > 0; off >>= 1) ex += __shfl_down(ex, off, 64);
    if (lane == 0) red[4 + wid] = ex;
    __syncthreads();
    if (tid == 0) ws[b] = gmx + __logf(red[4] + red[5] + red[6] + red[7]);
}

__global__ void crf_finalize_kernel(const float* __restrict__ ws,
                                    float* __restrict__ out) {
    float v = 0.f;
    if ((int)threadIdx.x < CB) v = ws[threadIdx.x] - ws[CB + threadIdx.x];
    #pragma unroll
    for (int off = 32; off > 0; off >>= 1) v += __shfl_down(v, off, 64);
    if (threadIdx.x == 0) out[0] = v * (1.f / CB);
}

extern "C" void kernel_launch(void* const* d_in, const int* in_sizes, int n_in,
                              void* d_out, int out_size, void* d_ws, size_t ws_size,
                              hipStream_t stream) {
    const float* emissions = (const float*)d_in[0];
    const int* tags = (const int*)d_in[1];
    const int* mask = (const int*)d_in[2];
    const float* trans = (const float*)d_in[3];
    float* out = (float*)d_out;
    float* ws = (float*)d_ws;

    crf_main_kernel<<<2 * CB, 512, 0, stream>>>(emissions, tags, mask, trans, ws);
    crf_combine_kernel<<<CB, CK, 0, stream>>>(ws);
    crf_finalize_kernel<<<1, 64, 0, stream>>>(ws, out);
}